// Round 21
// baseline (406.839 us; speedup 1.0000x reference)
//
#include <hip/hip_runtime.h>
#include <hip/hip_fp16.h>
#include <math.h>

// Problem constants (from reference)
#define NNODE  100000
#define NEDGE  3200000
#define DFEAT  256
#define NCLS   40
#define NC_TOT 4000000        // NNODE * NCLS
#define NIDS   1000
#define TOLSQ  1.0e-4f        // TOL^2, TOL = 0.01
#define MAXIT  16

#define SB 2048               // spmv blocks (contiguous chunks, XCD-swizzled)
#define SLOT8 500000          // NNODE * 5 class-octets
#define SPB8 245              // slots per chunk: ceil(SLOT8 / SB)
#define XB 1024               // blocks for streaming float4 kernels
#define VT 256
#define GR     128            // rows per gemm block (2 rows/thread, 4 cslots)
#define GEMM_B 782            // ceil(NNODE / GR)
#define GEMM_B2 1564          // split-K: 2 * GEMM_B (b&1 = K-half)
#define KHALF  128            // K elements per split half

// Bucketed CSR build
#define RB      128           // rows per bucket (row >> 7)
#define NBUCK   782           // ceil(NNODE / RB)
#define BCAP    6144          // LDS edge capacity per bucket in k_bbuild
#define SUBB    1024          // sub-buckets per bucket: 128 rows x 8 col-blocks
// Partition (counting sort) parameters
#define NPB     800           // partition blocks
#define EPB     4000          // edges per partition block (NPB*EPB == NEDGE)

__device__ __forceinline__ float block_reduce_256(float v, float* red) {
  int tid = threadIdx.x;
  red[tid] = v;
  __syncthreads();
  #pragma unroll
  for (int off = 128; off > 0; off >>= 1) {
    if (tid < off) red[tid] += red[tid + off];
    __syncthreads();
  }
  float res = red[0];
  __syncthreads();
  return res;
}

// ------------------- partition-based CSR build -------------------
__global__ void __launch_bounds__(256) k_pcount(const int* __restrict__ row,
                                                int* __restrict__ cntmat,
                                                int* __restrict__ total) {
  __shared__ int h[NBUCK];
  int tid = threadIdx.x, blk = blockIdx.x;
  for (int i = tid; i < NBUCK; i += 256) h[i] = 0;
  __syncthreads();
  int e0 = blk * EPB;
  for (int i = tid; i < EPB; i += 256) atomicAdd(&h[row[e0 + i] >> 7], 1);
  __syncthreads();
  for (int i = tid; i < NBUCK; i += 256) {
    int v = h[i];
    cntmat[blk * NBUCK + i] = v;
    if (v) atomicAdd(&total[i], v);
  }
}

__global__ void k_bscan2(const int* __restrict__ total, int* __restrict__ bptr) {
  __shared__ int s[1024];
  int tid = threadIdx.x;
  int v = (tid < NBUCK) ? total[tid] : 0;
  s[tid] = v;
  __syncthreads();
  for (int off = 1; off < 1024; off <<= 1) {
    int t = (tid >= off) ? s[tid - off] : 0;
    __syncthreads();
    s[tid] += t;
    __syncthreads();
  }
  if (tid < NBUCK) bptr[tid] = s[tid] - v;
  if (tid == 0) bptr[NBUCK] = NEDGE;
}

__global__ void __launch_bounds__(1024) k_colscan(int* __restrict__ cntmat,
                                                  const int* __restrict__ bptr) {
  __shared__ int s[1024];
  int b = blockIdx.x;
  int tid = threadIdx.x;
  int v = (tid < NPB) ? cntmat[tid * NBUCK + b] : 0;
  s[tid] = v;
  __syncthreads();
  for (int off = 1; off < 1024; off <<= 1) {
    int t = (tid >= off) ? s[tid - off] : 0;
    __syncthreads();
    s[tid] += t;
    __syncthreads();
  }
  if (tid < NPB) cntmat[tid * NBUCK + b] = bptr[b] + s[tid] - v;
}

// 512 threads: same LDS footprint (2 blocks/CU) but 16 waves/CU.
__global__ void __launch_bounds__(512) k_ppart(const int* __restrict__ row,
    const int* __restrict__ col, const float* __restrict__ data,
    const int* __restrict__ offmat, uint2* __restrict__ bstage) {
  __shared__ int cnt[NBUCK];
  __shared__ int segs[NBUCK + 1];
  __shared__ int cur[NBUCK];
  __shared__ int goff[NBUCK];
  __shared__ int scp[512];
  __shared__ unsigned short bof[EPB];
  __shared__ uint2 pay[EPB];
  int tid = threadIdx.x, blk = blockIdx.x;
  int e0 = blk * EPB;

  for (int i = tid; i < NBUCK; i += 512) {
    cnt[i] = 0;
    goff[i] = offmat[blk * NBUCK + i];
  }
  __syncthreads();
  for (int i = tid; i < EPB; i += 512) atomicAdd(&cnt[row[e0 + i] >> 7], 1);
  __syncthreads();

  int t2 = tid * 2;
  int l0 = (t2 + 0 < NBUCK) ? cnt[t2 + 0] : 0;
  int l1 = (t2 + 1 < NBUCK) ? cnt[t2 + 1] : 0;
  int mysum = l0 + l1;
  scp[tid] = mysum;
  __syncthreads();
  for (int off = 1; off < 512; off <<= 1) {
    int t = (tid >= off) ? scp[tid - off] : 0;
    __syncthreads();
    scp[tid] += t;
    __syncthreads();
  }
  int base = scp[tid] - mysum;
  if (t2 + 0 <= NBUCK) segs[t2 + 0] = base;  base += l0;
  if (t2 + 1 <= NBUCK) segs[t2 + 1] = base;
  for (int i = tid; i < NBUCK; i += 512) cur[i] = 0;
  __syncthreads();

  for (int b = tid; b < NBUCK; b += 512) {
    int s1 = segs[b + 1];
    for (int i = segs[b]; i < s1; ++i) bof[i] = (unsigned short)b;
  }
  for (int i = tid; i < EPB; i += 512) {
    int rr = row[e0 + i];
    int b = rr >> 7;
    int rk = atomicAdd(&cur[b], 1);
    pay[segs[b] + rk] = make_uint2(((unsigned)(rr & (RB - 1)) << 17) | (unsigned)col[e0 + i],
                                   __float_as_uint(data[e0 + i]));
  }
  __syncthreads();
  for (int i = tid; i < EPB; i += 512) {
    int b = bof[i];
    bstage[goff[b] + (i - segs[b])] = pay[i];
  }
}

// Build CSR; edges within a row sorted by col-block. 512 threads.
__global__ void __launch_bounds__(512) k_bbuild(const int* __restrict__ bptr,
    const uint2* __restrict__ bstage, int* __restrict__ rowptr,
    int2* __restrict__ csr) {
  __shared__ uint2 ebuf[BCAP];   // 48KB
  __shared__ int deg[SUBB];      // 4KB (reused as scatter cursor)
  __shared__ int segs[SUBB];     // 4KB exclusive scan
  __shared__ int scp[512];
  int b = blockIdx.x;
  int s0 = bptr[b], s1 = bptr[b + 1];
  int n = s1 - s0;
  if (n > BCAP) n = BCAP;
  int tid = threadIdx.x;
  for (int i = tid; i < SUBB; i += 512) deg[i] = 0;
  __syncthreads();
  for (int i = tid; i < n; i += 512) {
    uint2 e = bstage[s0 + i];
    ebuf[i] = e;
    int key = (int)(e.x >> 17) * 8 + (int)((e.x & 0x1FFFF) >> 14);
    atomicAdd(&deg[key], 1);
  }
  __syncthreads();
  int t2 = tid * 2;
  int l0 = deg[t2 + 0], l1 = deg[t2 + 1];
  int mysum = l0 + l1;
  scp[tid] = mysum;
  __syncthreads();
  for (int off = 1; off < 512; off <<= 1) {
    int t = (tid >= off) ? scp[tid - off] : 0;
    __syncthreads();
    scp[tid] += t;
    __syncthreads();
  }
  int base = scp[tid] - mysum;
  segs[t2 + 0] = base;  base += l0;
  segs[t2 + 1] = base;
  __syncthreads();
  for (int i = tid; i < SUBB; i += 512) deg[i] = 0;
  if (tid < RB) {
    int grow = b * RB + tid;
    if (grow < NNODE) rowptr[grow] = s0 + segs[tid * 8];
  }
  if (b == 0 && tid == 0) rowptr[NNODE] = NEDGE;
  __syncthreads();
  for (int i = tid; i < n; i += 512) {
    uint2 e = ebuf[i];
    int col = (int)(e.x & 0x1FFFF);
    int key = (int)(e.x >> 17) * 8 + (col >> 14);
    int pos = atomicAdd(&deg[key], 1);
    csr[s0 + segs[key] + pos] = make_int2(col, (int)e.y);
  }
}

// ------------------- init: b_vec = X@W + b (split-K x2) ----------------------
// 1564 blocks: b&1 = K-half, b>>1 = row block. Each block stages only its
// 128x40 W-half (20.5KB LDS -> ~7 blocks/CU resident vs 3) -> 2x waves/CU
// on the latency-bound feat stream. Barrier-free inner loop (r20).
__global__ void __launch_bounds__(256) k_gemm(const float* __restrict__ feat,
    const float* __restrict__ W, const float* __restrict__ bias,
    float* __restrict__ pb0, float* __restrict__ pb1) {
  __shared__ float wtile[KHALF * NCLS];   // 20.5KB: this half of W
  int tid = threadIdx.x;
  int b = blockIdx.x;
  int half = b & 1;
  int r0 = (b >> 1) * GR;
  int rl0 = (tid >> 2) * 2;
  int cbase = (tid & 3) * 10;
  float acc0[10], acc1[10];
  #pragma unroll
  for (int j = 0; j < 10; ++j) {
    float bv = half ? 0.f : bias[cbase + j];   // bias seeded in half 0 only
    acc0[j] = bv;
    acc1[j] = bv;
  }

  // stage this K-half of W (5120 floats, 20/thread, coalesced); one barrier
  #pragma unroll
  for (int it = 0; it < KHALF * NCLS / 256; ++it)
    wtile[tid + it * 256] = W[half * KHALF * NCLS + tid + it * 256];
  __syncthreads();

  int g0 = r0 + rl0, g1 = g0 + 1;
  int g0c = (g0 < NNODE) ? g0 : NNODE - 1;   // clamp reads; writes guarded
  int g1c = (g1 < NNODE) ? g1 : NNODE - 1;
  const float* f0p = feat + (size_t)g0c * DFEAT + half * KHALF;
  const float* f1p = feat + (size_t)g1c * DFEAT + half * KHALF;

  #pragma unroll 4
  for (int kq = 0; kq < KHALF / 4; ++kq) {
    float4 f0 = *(const float4*)(f0p + kq * 4);
    float4 f1 = *(const float4*)(f1p + kq * 4);
    const float* w0 = &wtile[(kq * 4 + 0) * NCLS + cbase];
    const float* w1 = &wtile[(kq * 4 + 1) * NCLS + cbase];
    const float* w2 = &wtile[(kq * 4 + 2) * NCLS + cbase];
    const float* w3 = &wtile[(kq * 4 + 3) * NCLS + cbase];
    #pragma unroll
    for (int j = 0; j < 10; ++j) {
      float wa = w0[j], wb = w1[j], wc = w2[j], wd = w3[j];
      acc0[j] = fmaf(f0.x, wa, acc0[j]);
      acc0[j] = fmaf(f0.y, wb, acc0[j]);
      acc0[j] = fmaf(f0.z, wc, acc0[j]);
      acc0[j] = fmaf(f0.w, wd, acc0[j]);
      acc1[j] = fmaf(f1.x, wa, acc1[j]);
      acc1[j] = fmaf(f1.y, wb, acc1[j]);
      acc1[j] = fmaf(f1.z, wc, acc1[j]);
      acc1[j] = fmaf(f1.w, wd, acc1[j]);
    }
  }

  float* __restrict__ pb = half ? pb1 : pb0;
  if (g0 < NNODE) {
    size_t b0 = (size_t)g0 * NCLS + cbase;
    #pragma unroll
    for (int j = 0; j < 10; ++j) pb[b0 + j] = acc0[j];
  }
  if (g1 < NNODE) {
    size_t b1 = (size_t)g1 * NCLS + cbase;
    #pragma unroll
    for (int j = 0; j < 10; ++j) pb[b1 + j] = acc1[j];
  }
}

// combine: b = pb0 + pb1; r = p = b (+fp16 mirror); <b,b> partials
__global__ void __launch_bounds__(VT) k_gcomb(const float* __restrict__ pb0,
    const float* __restrict__ pb1, float* __restrict__ r, float* __restrict__ p,
    __half* __restrict__ ph, float* __restrict__ part) {
  __shared__ float red[256];
  const float4* a4 = (const float4*)pb0;
  const float4* b4 = (const float4*)pb1;
  float4* r4 = (float4*)r;
  float4* p4 = (float4*)p;
  float local = 0.f;
  int stride = gridDim.x * blockDim.x;
  for (int e = blockIdx.x * blockDim.x + threadIdx.x; e < NC_TOT / 4; e += stride) {
    float4 a = a4[e], b = b4[e];
    float4 v;
    v.x = a.x + b.x; v.y = a.y + b.y; v.z = a.z + b.z; v.w = a.w + b.w;
    r4[e] = v; p4[e] = v;
    __half2 h01 = __floats2half2_rn(v.x, v.y);
    __half2 h23 = __floats2half2_rn(v.z, v.w);
    uint2 pack;
    pack.x = *(unsigned*)&h01;
    pack.y = *(unsigned*)&h23;
    *(uint2*)(ph + (size_t)e * 4) = pack;
    local = fmaf(v.x, v.x, local); local = fmaf(v.y, v.y, local);
    local = fmaf(v.z, v.z, local); local = fmaf(v.w, v.w, local);
  }
  float tot = block_reduce_256(local, red);
  if (threadIdx.x == 0) part[blockIdx.x] = tot;
}

// scalars: scal[0]=omega(=1-eps), scal[1]=atol2, scal[2+k]=gamma_k
__global__ void k_init_scal(const float* __restrict__ part, const float* __restrict__ e0,
                            float* __restrict__ scal) {
  __shared__ float red[256];
  float local = 0.f;
  for (int i = threadIdx.x; i < XB; i += 256) local += part[i];
  float bs = block_reduce_256(local, red);
  if (threadIdx.x == 0) {
    float eps = 1.f / (1.f + expf(-e0[0]));
    scal[0] = 1.f - eps;
    scal[1] = TOLSQ * bs;
    scal[2] = bs;          // gamma_0 = <r0,r0> = <b,b>
  }
}

// ------------------- CG iteration kernels (device-side convergence guard) ---
// 8-class-per-thread spmv: thread owns (row, class-octet), gathers uint4
// (8 halves, 16B-aligned) per edge.
__global__ void __launch_bounds__(VT) k_spmv(const float* __restrict__ scal, int k,
    const int* __restrict__ rowptr, const int2* __restrict__ csr,
    const __half* __restrict__ ph, const float* __restrict__ p,
    float* __restrict__ Ap, float* __restrict__ part) {
  float gamma = scal[2 + k], atol2 = scal[1];
  if (!(gamma > atol2)) return;               // mirrors JAX while cond (rs > atol2)
  float omega = scal[0];
  int b = blockIdx.x;
  int chunk = (b & 7) * (SB / 8) + (b >> 3);  // bijective: 2048 = 8 * 256
  int sbase = chunk * SPB8;
  float local = 0.f;
  int li = threadIdx.x;                       // SPB8=245 <= 256: one slot/thread
  int s = sbase + li;
  if (li < SPB8 && s < SLOT8) {
    int rr = s / 5;
    int c8 = (s - rr * 5) * 8;                // class offset 0,8,16,24,32
    int s0 = rowptr[rr], s1 = rowptr[rr + 1];
    float a0 = 0.f, a1 = 0.f, a2 = 0.f, a3 = 0.f;
    float a4 = 0.f, a5 = 0.f, a6 = 0.f, a7 = 0.f;
    #pragma unroll 4
    for (int j = s0; j < s1; ++j) {
      int2 pr = csr[j];
      float w = __int_as_float(pr.y);
      uint4 g = *(const uint4*)(ph + (size_t)pr.x * NCLS + c8);
      float2 f01 = __half22float2(*(__half2*)&g.x);
      float2 f23 = __half22float2(*(__half2*)&g.y);
      float2 f45 = __half22float2(*(__half2*)&g.z);
      float2 f67 = __half22float2(*(__half2*)&g.w);
      a0 = fmaf(w, f01.x, a0); a1 = fmaf(w, f01.y, a1);
      a2 = fmaf(w, f23.x, a2); a3 = fmaf(w, f23.y, a3);
      a4 = fmaf(w, f45.x, a4); a5 = fmaf(w, f45.y, a5);
      a6 = fmaf(w, f67.x, a6); a7 = fmaf(w, f67.y, a7);
    }
    size_t e = (size_t)rr * NCLS + c8;
    float4 pe0 = *(const float4*)(p + e);
    float4 pe1 = *(const float4*)(p + e + 4);
    float4 v0, v1;
    v0.x = fmaf(-omega, a0, pe0.x); v0.y = fmaf(-omega, a1, pe0.y);
    v0.z = fmaf(-omega, a2, pe0.z); v0.w = fmaf(-omega, a3, pe0.w);
    v1.x = fmaf(-omega, a4, pe1.x); v1.y = fmaf(-omega, a5, pe1.y);
    v1.z = fmaf(-omega, a6, pe1.z); v1.w = fmaf(-omega, a7, pe1.w);
    *(float4*)(Ap + e) = v0;
    *(float4*)(Ap + e + 4) = v1;
    local = fmaf(pe0.x, v0.x, local); local = fmaf(pe0.y, v0.y, local);
    local = fmaf(pe0.z, v0.z, local); local = fmaf(pe0.w, v0.w, local);
    local = fmaf(pe1.x, v1.x, local); local = fmaf(pe1.y, v1.y, local);
    local = fmaf(pe1.z, v1.z, local); local = fmaf(pe1.w, v1.w, local);
  }
  __shared__ float red[256];
  float tot = block_reduce_256(local, red);
  if (threadIdx.x == 0) part[blockIdx.x] = tot;
}

// xr: alpha = gamma/<p,Ap>; r -= alpha*Ap (+ <r',r'> partials);
// first blocks also accumulate the output logits: out += alpha * p[ids]
__global__ void __launch_bounds__(VT) k_xr(const float* __restrict__ scal, int k,
    const float* __restrict__ part_in,
    const float* __restrict__ p, const float* __restrict__ Ap,
    float* __restrict__ r, const int* __restrict__ ids,
    float* __restrict__ out, float* __restrict__ part_out) {
  float gamma = scal[2 + k], atol2 = scal[1];
  if (!(gamma > atol2)) return;
  __shared__ float red[256];
  float lp = 0.f;
  for (int i = threadIdx.x; i < SB; i += VT) lp += part_in[i];
  float pap = block_reduce_256(lp, red);      // identical in every block
  float alpha = gamma / pap;
  // output accumulation (x only ever needed at ids): 157 blocks cover 40000
  int idx = blockIdx.x * VT + threadIdx.x;
  if (idx < NIDS * NCLS) {
    int i = idx / NCLS, c = idx - (idx / NCLS) * NCLS;
    out[idx] += alpha * p[(size_t)ids[i] * NCLS + c];
  }
  const float4* a4 = (const float4*)Ap;
  float4* r4 = (float4*)r;
  float local = 0.f;
  int stride = gridDim.x * blockDim.x;
  for (int e = blockIdx.x * blockDim.x + threadIdx.x; e < NC_TOT / 4; e += stride) {
    float4 ae = a4[e], re = r4[e];
    re.x = fmaf(-alpha, ae.x, re.x); re.y = fmaf(-alpha, ae.y, re.y);
    re.z = fmaf(-alpha, ae.z, re.z); re.w = fmaf(-alpha, ae.w, re.w);
    r4[e] = re;
    local = fmaf(re.x, re.x, local); local = fmaf(re.y, re.y, local);
    local = fmaf(re.z, re.z, local); local = fmaf(re.w, re.w, local);
  }
  float tot = block_reduce_256(local, red);
  if (threadIdx.x == 0) part_out[blockIdx.x] = tot;
}

__global__ void __launch_bounds__(VT) k_pupd(float* __restrict__ scal, int k,
    const float* __restrict__ part_in,
    const float* __restrict__ r, float* __restrict__ p, __half* __restrict__ ph) {
  float gamma = scal[2 + k], atol2 = scal[1];
  if (!(gamma > atol2)) {
    if (blockIdx.x == 0 && threadIdx.x == 0) scal[2 + k + 1] = gamma;  // propagate
    return;
  }
  __shared__ float red[256];
  float lp = 0.f;
  for (int i = threadIdx.x; i < XB; i += VT) lp += part_in[i];
  float gnew = block_reduce_256(lp, red);
  float beta = gnew / gamma;
  const float4* r4 = (const float4*)r;
  float4* p4 = (float4*)p;
  int stride = gridDim.x * blockDim.x;
  for (int e = blockIdx.x * blockDim.x + threadIdx.x; e < NC_TOT / 4; e += stride) {
    float4 pe = p4[e], re = r4[e];
    pe.x = fmaf(beta, pe.x, re.x); pe.y = fmaf(beta, pe.y, re.y);
    pe.z = fmaf(beta, pe.z, re.z); pe.w = fmaf(beta, pe.w, re.w);
    p4[e] = pe;
    int e4 = e * 4;
    ph[e4 + 0] = __float2half(pe.x);
    ph[e4 + 1] = __float2half(pe.y);
    ph[e4 + 2] = __float2half(pe.z);
    ph[e4 + 3] = __float2half(pe.w);
  }
  if (blockIdx.x == 0 && threadIdx.x == 0) scal[2 + k + 1] = gnew;
}

// ------------------- host launch -------------------
extern "C" void kernel_launch(void* const* d_in, const int* in_sizes, int n_in,
                              void* d_out, int out_size, void* d_ws, size_t ws_size,
                              hipStream_t stream) {
  const float* feat = (const float*)d_in[0];
  const float* W    = (const float*)d_in[1];
  const float* bias = (const float*)d_in[2];
  const float* e0   = (const float*)d_in[3];
  const float* data = (const float*)d_in[4];
  const int*   row  = (const int*)d_in[5];
  const int*   col  = (const int*)d_in[6];
  const int*   ids  = (const int*)d_in[7];
  float* out = (float*)d_out;

  size_t off = 0;
  char* base = (char*)d_ws;
  auto take = [&](size_t nbytes) -> void* {
    void* ptr = base + off;
    off += (nbytes + 255) & ~(size_t)255;
    return ptr;
  };
  float* rv  = (float*)take((size_t)NC_TOT * 4);
  float* pv  = (float*)take((size_t)NC_TOT * 4);
  float* ap  = (float*)take((size_t)NC_TOT * 4);    // doubles as pb0 (dead pre-CG)
  float* pb1 = (float*)take((size_t)NC_TOT * 4);
  __half* ph = (__half*)take((size_t)NC_TOT * 2);
  int2*  csr = (int2*)take((size_t)NEDGE * 8);
  int* rowptr    = (int*)take((size_t)(NNODE + 1) * 4);
  int* cntmat    = (int*)take((size_t)NPB * NBUCK * 4);   // becomes offmat in-place
  int* total     = (int*)take((size_t)(NBUCK + 2) * 4);
  int* bptr      = (int*)take((size_t)(NBUCK + 2) * 4);
  float* part_a  = (float*)take(SB * 4);
  float* part_b  = (float*)take(XB * 4);
  float* scal    = (float*)take(64 * 4);

  // bucket staging buffer aliases rv+pv (25.6MB <= 32MB); dead before k_gcomb
  uint2* bstage = (uint2*)rv;
  float* pb0 = ap;   // split-K partial 0 aliases ap (dead until first spmv)

  // partition-based CSR build
  hipMemsetAsync(total, 0, (size_t)(NBUCK + 2) * 4, stream);
  hipMemsetAsync(out, 0, (size_t)NIDS * NCLS * 4, stream);
  k_pcount<<<NPB, 256, 0, stream>>>(row, cntmat, total);
  k_bscan2<<<1, 1024, 0, stream>>>(total, bptr);
  k_colscan<<<NBUCK, 1024, 0, stream>>>(cntmat, bptr);
  k_ppart<<<NPB, 512, 0, stream>>>(row, col, data, cntmat, bstage);
  k_bbuild<<<NBUCK, 512, 0, stream>>>(bptr, bstage, rowptr, csr);

  // init: split-K gemm -> combine (r=p=b, fp16 mirror, <b,b> partials)
  k_gemm<<<GEMM_B2, 256, 0, stream>>>(feat, W, bias, pb0, pb1);
  k_gcomb<<<XB, VT, 0, stream>>>(pb0, pb1, rv, pv, ph, part_b);
  k_init_scal<<<1, 256, 0, stream>>>(part_b, e0, scal);

  // 16 unrolled, device-guarded CG iterations
  for (int k = 0; k < MAXIT; ++k) {
    k_spmv<<<SB, VT, 0, stream>>>(scal, k, rowptr, csr, ph, pv, ap, part_a);
    k_xr  <<<XB, VT, 0, stream>>>(scal, k, part_a, pv, ap, rv, ids, out, part_b);
    k_pupd<<<XB, VT, 0, stream>>>(scal, k, part_b, rv, pv, ph);
  }
}

// Round 22
// 389.052 us; speedup vs baseline: 1.0457x; 1.0457x over previous
//
#include <hip/hip_runtime.h>
#include <hip/hip_fp16.h>
#include <math.h>

// Problem constants (from reference)
#define NNODE  100000
#define NEDGE  3200000
#define DFEAT  256
#define NCLS   40
#define NC_TOT 4000000        // NNODE * NCLS
#define NIDS   1000
#define TOLSQ  1.0e-4f        // TOL^2, TOL = 0.01
#define MAXIT  16

#define SB 2048               // spmv blocks (contiguous chunks, XCD-swizzled)
#define SLOT8 500000          // NNODE * 5 class-octets
#define SPB8 245              // slots per chunk: ceil(SLOT8 / SB)
#define XB 1024               // blocks for streaming float4 kernels
#define VT 256
#define GR     128            // rows per gemm block (2 rows/thread, 4 cslots)
#define GEMM_B 782            // ceil(NNODE / GR)

// Bucketed CSR build
#define RB      128           // rows per bucket (row >> 7)
#define NBUCK   782           // ceil(NNODE / RB)
#define BCAP    6144          // LDS edge capacity per bucket in k_bbuild
#define SUBB    1024          // sub-buckets per bucket: 128 rows x 8 col-blocks
// Partition (counting sort) parameters
#define NPB     800           // partition blocks
#define EPB     4000          // edges per partition block (NPB*EPB == NEDGE)

__device__ __forceinline__ float block_reduce_256(float v, float* red) {
  int tid = threadIdx.x;
  red[tid] = v;
  __syncthreads();
  #pragma unroll
  for (int off = 128; off > 0; off >>= 1) {
    if (tid < off) red[tid] += red[tid + off];
    __syncthreads();
  }
  float res = red[0];
  __syncthreads();
  return res;
}

// ------------------- partition-based CSR build -------------------
__global__ void __launch_bounds__(256) k_pcount(const int* __restrict__ row,
                                                int* __restrict__ cntmat,
                                                int* __restrict__ total) {
  __shared__ int h[NBUCK];
  int tid = threadIdx.x, blk = blockIdx.x;
  for (int i = tid; i < NBUCK; i += 256) h[i] = 0;
  __syncthreads();
  int e0 = blk * EPB;
  for (int i = tid; i < EPB; i += 256) atomicAdd(&h[row[e0 + i] >> 7], 1);
  __syncthreads();
  for (int i = tid; i < NBUCK; i += 256) {
    int v = h[i];
    cntmat[blk * NBUCK + i] = v;
    if (v) atomicAdd(&total[i], v);
  }
}

__global__ void k_bscan2(const int* __restrict__ total, int* __restrict__ bptr) {
  __shared__ int s[1024];
  int tid = threadIdx.x;
  int v = (tid < NBUCK) ? total[tid] : 0;
  s[tid] = v;
  __syncthreads();
  for (int off = 1; off < 1024; off <<= 1) {
    int t = (tid >= off) ? s[tid - off] : 0;
    __syncthreads();
    s[tid] += t;
    __syncthreads();
  }
  if (tid < NBUCK) bptr[tid] = s[tid] - v;
  if (tid == 0) bptr[NBUCK] = NEDGE;
}

__global__ void __launch_bounds__(1024) k_colscan(int* __restrict__ cntmat,
                                                  const int* __restrict__ bptr) {
  __shared__ int s[1024];
  int b = blockIdx.x;
  int tid = threadIdx.x;
  int v = (tid < NPB) ? cntmat[tid * NBUCK + b] : 0;
  s[tid] = v;
  __syncthreads();
  for (int off = 1; off < 1024; off <<= 1) {
    int t = (tid >= off) ? s[tid - off] : 0;
    __syncthreads();
    s[tid] += t;
    __syncthreads();
  }
  if (tid < NPB) cntmat[tid * NBUCK + b] = bptr[b] + s[tid] - v;
}

// 512 threads: same LDS footprint (2 blocks/CU) but 16 waves/CU.
__global__ void __launch_bounds__(512) k_ppart(const int* __restrict__ row,
    const int* __restrict__ col, const float* __restrict__ data,
    const int* __restrict__ offmat, uint2* __restrict__ bstage) {
  __shared__ int cnt[NBUCK];
  __shared__ int segs[NBUCK + 1];
  __shared__ int cur[NBUCK];
  __shared__ int goff[NBUCK];
  __shared__ int scp[512];
  __shared__ unsigned short bof[EPB];
  __shared__ uint2 pay[EPB];
  int tid = threadIdx.x, blk = blockIdx.x;
  int e0 = blk * EPB;

  for (int i = tid; i < NBUCK; i += 512) {
    cnt[i] = 0;
    goff[i] = offmat[blk * NBUCK + i];
  }
  __syncthreads();
  for (int i = tid; i < EPB; i += 512) atomicAdd(&cnt[row[e0 + i] >> 7], 1);
  __syncthreads();

  int t2 = tid * 2;
  int l0 = (t2 + 0 < NBUCK) ? cnt[t2 + 0] : 0;
  int l1 = (t2 + 1 < NBUCK) ? cnt[t2 + 1] : 0;
  int mysum = l0 + l1;
  scp[tid] = mysum;
  __syncthreads();
  for (int off = 1; off < 512; off <<= 1) {
    int t = (tid >= off) ? scp[tid - off] : 0;
    __syncthreads();
    scp[tid] += t;
    __syncthreads();
  }
  int base = scp[tid] - mysum;
  if (t2 + 0 <= NBUCK) segs[t2 + 0] = base;  base += l0;
  if (t2 + 1 <= NBUCK) segs[t2 + 1] = base;
  for (int i = tid; i < NBUCK; i += 512) cur[i] = 0;
  __syncthreads();

  for (int b = tid; b < NBUCK; b += 512) {
    int s1 = segs[b + 1];
    for (int i = segs[b]; i < s1; ++i) bof[i] = (unsigned short)b;
  }
  for (int i = tid; i < EPB; i += 512) {
    int rr = row[e0 + i];
    int b = rr >> 7;
    int rk = atomicAdd(&cur[b], 1);
    pay[segs[b] + rk] = make_uint2(((unsigned)(rr & (RB - 1)) << 17) | (unsigned)col[e0 + i],
                                   __float_as_uint(data[e0 + i]));
  }
  __syncthreads();
  for (int i = tid; i < EPB; i += 512) {
    int b = bof[i];
    bstage[goff[b] + (i - segs[b])] = pay[i];
  }
}

// Build CSR; edges within a row sorted by col-block. 512 threads.
__global__ void __launch_bounds__(512) k_bbuild(const int* __restrict__ bptr,
    const uint2* __restrict__ bstage, int* __restrict__ rowptr,
    int2* __restrict__ csr) {
  __shared__ uint2 ebuf[BCAP];   // 48KB
  __shared__ int deg[SUBB];      // 4KB (reused as scatter cursor)
  __shared__ int segs[SUBB];     // 4KB exclusive scan
  __shared__ int scp[512];
  int b = blockIdx.x;
  int s0 = bptr[b], s1 = bptr[b + 1];
  int n = s1 - s0;
  if (n > BCAP) n = BCAP;
  int tid = threadIdx.x;
  for (int i = tid; i < SUBB; i += 512) deg[i] = 0;
  __syncthreads();
  for (int i = tid; i < n; i += 512) {
    uint2 e = bstage[s0 + i];
    ebuf[i] = e;
    int key = (int)(e.x >> 17) * 8 + (int)((e.x & 0x1FFFF) >> 14);
    atomicAdd(&deg[key], 1);
  }
  __syncthreads();
  int t2 = tid * 2;
  int l0 = deg[t2 + 0], l1 = deg[t2 + 1];
  int mysum = l0 + l1;
  scp[tid] = mysum;
  __syncthreads();
  for (int off = 1; off < 512; off <<= 1) {
    int t = (tid >= off) ? scp[tid - off] : 0;
    __syncthreads();
    scp[tid] += t;
    __syncthreads();
  }
  int base = scp[tid] - mysum;
  segs[t2 + 0] = base;  base += l0;
  segs[t2 + 1] = base;
  __syncthreads();
  for (int i = tid; i < SUBB; i += 512) deg[i] = 0;
  if (tid < RB) {
    int grow = b * RB + tid;
    if (grow < NNODE) rowptr[grow] = s0 + segs[tid * 8];
  }
  if (b == 0 && tid == 0) rowptr[NNODE] = NEDGE;
  __syncthreads();
  for (int i = tid; i < n; i += 512) {
    uint2 e = ebuf[i];
    int col = (int)(e.x & 0x1FFFF);
    int key = (int)(e.x >> 17) * 8 + (col >> 14);
    int pos = atomicAdd(&deg[key], 1);
    csr[s0 + segs[key] + pos] = make_int2(col, (int)e.y);
  }
}

// ------------------- init: b_vec = X@W + b; r=p=b_vec (+fp16 mirror) --------
// Barrier-free GEMM (r20, measured optimum): whole W in LDS once; feat read
// directly from global (same-address merge across the 4 lanes of a row-pair).
__global__ void __launch_bounds__(256) k_gemm(const float* __restrict__ feat,
    const float* __restrict__ W, const float* __restrict__ bias,
    float* __restrict__ r, float* __restrict__ p, __half* __restrict__ ph,
    float* __restrict__ part) {
  __shared__ float wtile[DFEAT * NCLS];   // 40KB: all of W
  __shared__ float red[256];
  int tid = threadIdx.x;
  int r0 = blockIdx.x * GR;
  int rl0 = (tid >> 2) * 2;
  int cbase = (tid & 3) * 10;
  float acc0[10], acc1[10];
  #pragma unroll
  for (int j = 0; j < 10; ++j) {
    float bv = bias[cbase + j];
    acc0[j] = bv;
    acc1[j] = bv;
  }

  // stage all of W (10240 floats, 40/thread, coalesced); single barrier
  #pragma unroll
  for (int it = 0; it < DFEAT * NCLS / 256; ++it)
    wtile[tid + it * 256] = W[tid + it * 256];
  __syncthreads();

  int g0 = r0 + rl0, g1 = g0 + 1;
  int g0c = (g0 < NNODE) ? g0 : NNODE - 1;   // clamp reads; writes guarded
  int g1c = (g1 < NNODE) ? g1 : NNODE - 1;
  const float* f0p = feat + (size_t)g0c * DFEAT;
  const float* f1p = feat + (size_t)g1c * DFEAT;

  #pragma unroll 4
  for (int kq = 0; kq < DFEAT / 4; ++kq) {
    float4 f0 = *(const float4*)(f0p + kq * 4);
    float4 f1 = *(const float4*)(f1p + kq * 4);
    const float* w0 = &wtile[(kq * 4 + 0) * NCLS + cbase];
    const float* w1 = &wtile[(kq * 4 + 1) * NCLS + cbase];
    const float* w2 = &wtile[(kq * 4 + 2) * NCLS + cbase];
    const float* w3 = &wtile[(kq * 4 + 3) * NCLS + cbase];
    #pragma unroll
    for (int j = 0; j < 10; ++j) {
      float wa = w0[j], wb = w1[j], wc = w2[j], wd = w3[j];
      acc0[j] = fmaf(f0.x, wa, acc0[j]);
      acc0[j] = fmaf(f0.y, wb, acc0[j]);
      acc0[j] = fmaf(f0.z, wc, acc0[j]);
      acc0[j] = fmaf(f0.w, wd, acc0[j]);
      acc1[j] = fmaf(f1.x, wa, acc1[j]);
      acc1[j] = fmaf(f1.y, wb, acc1[j]);
      acc1[j] = fmaf(f1.z, wc, acc1[j]);
      acc1[j] = fmaf(f1.w, wd, acc1[j]);
    }
  }

  float local = 0.f;
  if (g0 < NNODE) {
    size_t b0 = (size_t)g0 * NCLS + cbase;
    #pragma unroll
    for (int j = 0; j < 10; ++j) {
      float a = acc0[j];
      r[b0 + j] = a; p[b0 + j] = a; ph[b0 + j] = __float2half(a);
      local = fmaf(a, a, local);
    }
  }
  if (g1 < NNODE) {
    size_t b1 = (size_t)g1 * NCLS + cbase;
    #pragma unroll
    for (int j = 0; j < 10; ++j) {
      float a = acc1[j];
      r[b1 + j] = a; p[b1 + j] = a; ph[b1 + j] = __float2half(a);
      local = fmaf(a, a, local);
    }
  }
  float tot = block_reduce_256(local, red);
  if (tid == 0) part[blockIdx.x] = tot;
}

// scalars: scal[0]=omega(=1-eps), scal[1]=atol2, scal[2+k]=gamma_k
__global__ void k_init_scal(const float* __restrict__ part, const float* __restrict__ e0,
                            float* __restrict__ scal) {
  __shared__ float red[256];
  float local = 0.f;
  for (int i = threadIdx.x; i < GEMM_B; i += 256) local += part[i];
  float bs = block_reduce_256(local, red);
  if (threadIdx.x == 0) {
    float eps = 1.f / (1.f + expf(-e0[0]));
    scal[0] = 1.f - eps;
    scal[1] = TOLSQ * bs;
    scal[2] = bs;          // gamma_0 = <r0,r0> = <b,b>
  }
}

// ------------------- CG iteration kernels (device-side convergence guard) ---
// 8-class-per-thread spmv: thread owns (row, class-octet), gathers uint4
// (8 halves, 16B-aligned) per edge.
__global__ void __launch_bounds__(VT) k_spmv(const float* __restrict__ scal, int k,
    const int* __restrict__ rowptr, const int2* __restrict__ csr,
    const __half* __restrict__ ph, const float* __restrict__ p,
    float* __restrict__ Ap, float* __restrict__ part) {
  float gamma = scal[2 + k], atol2 = scal[1];
  if (!(gamma > atol2)) return;               // mirrors JAX while cond (rs > atol2)
  float omega = scal[0];
  int b = blockIdx.x;
  int chunk = (b & 7) * (SB / 8) + (b >> 3);  // bijective: 2048 = 8 * 256
  int sbase = chunk * SPB8;
  float local = 0.f;
  int li = threadIdx.x;                       // SPB8=245 <= 256: one slot/thread
  int s = sbase + li;
  if (li < SPB8 && s < SLOT8) {
    int rr = s / 5;
    int c8 = (s - rr * 5) * 8;                // class offset 0,8,16,24,32
    int s0 = rowptr[rr], s1 = rowptr[rr + 1];
    float a0 = 0.f, a1 = 0.f, a2 = 0.f, a3 = 0.f;
    float a4 = 0.f, a5 = 0.f, a6 = 0.f, a7 = 0.f;
    #pragma unroll 4
    for (int j = s0; j < s1; ++j) {
      int2 pr = csr[j];
      float w = __int_as_float(pr.y);
      uint4 g = *(const uint4*)(ph + (size_t)pr.x * NCLS + c8);
      float2 f01 = __half22float2(*(__half2*)&g.x);
      float2 f23 = __half22float2(*(__half2*)&g.y);
      float2 f45 = __half22float2(*(__half2*)&g.z);
      float2 f67 = __half22float2(*(__half2*)&g.w);
      a0 = fmaf(w, f01.x, a0); a1 = fmaf(w, f01.y, a1);
      a2 = fmaf(w, f23.x, a2); a3 = fmaf(w, f23.y, a3);
      a4 = fmaf(w, f45.x, a4); a5 = fmaf(w, f45.y, a5);
      a6 = fmaf(w, f67.x, a6); a7 = fmaf(w, f67.y, a7);
    }
    size_t e = (size_t)rr * NCLS + c8;
    float4 pe0 = *(const float4*)(p + e);
    float4 pe1 = *(const float4*)(p + e + 4);
    float4 v0, v1;
    v0.x = fmaf(-omega, a0, pe0.x); v0.y = fmaf(-omega, a1, pe0.y);
    v0.z = fmaf(-omega, a2, pe0.z); v0.w = fmaf(-omega, a3, pe0.w);
    v1.x = fmaf(-omega, a4, pe1.x); v1.y = fmaf(-omega, a5, pe1.y);
    v1.z = fmaf(-omega, a6, pe1.z); v1.w = fmaf(-omega, a7, pe1.w);
    *(float4*)(Ap + e) = v0;
    *(float4*)(Ap + e + 4) = v1;
    local = fmaf(pe0.x, v0.x, local); local = fmaf(pe0.y, v0.y, local);
    local = fmaf(pe0.z, v0.z, local); local = fmaf(pe0.w, v0.w, local);
    local = fmaf(pe1.x, v1.x, local); local = fmaf(pe1.y, v1.y, local);
    local = fmaf(pe1.z, v1.z, local); local = fmaf(pe1.w, v1.w, local);
  }
  __shared__ float red[256];
  float tot = block_reduce_256(local, red);
  if (threadIdx.x == 0) part[blockIdx.x] = tot;
}

// xr: alpha = gamma/<p,Ap>; r -= alpha*Ap (+ <r',r'> partials);
// first blocks also accumulate the output logits: out += alpha * p[ids]
__global__ void __launch_bounds__(VT) k_xr(const float* __restrict__ scal, int k,
    const float* __restrict__ part_in,
    const float* __restrict__ p, const float* __restrict__ Ap,
    float* __restrict__ r, const int* __restrict__ ids,
    float* __restrict__ out, float* __restrict__ part_out) {
  float gamma = scal[2 + k], atol2 = scal[1];
  if (!(gamma > atol2)) return;
  __shared__ float red[256];
  float lp = 0.f;
  for (int i = threadIdx.x; i < SB; i += VT) lp += part_in[i];
  float pap = block_reduce_256(lp, red);      // identical in every block
  float alpha = gamma / pap;
  // output accumulation (x only ever needed at ids): 157 blocks cover 40000
  int idx = blockIdx.x * VT + threadIdx.x;
  if (idx < NIDS * NCLS) {
    int i = idx / NCLS, c = idx - (idx / NCLS) * NCLS;
    out[idx] += alpha * p[(size_t)ids[i] * NCLS + c];
  }
  const float4* a4 = (const float4*)Ap;
  float4* r4 = (float4*)r;
  float local = 0.f;
  int stride = gridDim.x * blockDim.x;
  for (int e = blockIdx.x * blockDim.x + threadIdx.x; e < NC_TOT / 4; e += stride) {
    float4 ae = a4[e], re = r4[e];
    re.x = fmaf(-alpha, ae.x, re.x); re.y = fmaf(-alpha, ae.y, re.y);
    re.z = fmaf(-alpha, ae.z, re.z); re.w = fmaf(-alpha, ae.w, re.w);
    r4[e] = re;
    local = fmaf(re.x, re.x, local); local = fmaf(re.y, re.y, local);
    local = fmaf(re.z, re.z, local); local = fmaf(re.w, re.w, local);
  }
  float tot = block_reduce_256(local, red);
  if (threadIdx.x == 0) part_out[blockIdx.x] = tot;
}

__global__ void __launch_bounds__(VT) k_pupd(float* __restrict__ scal, int k,
    const float* __restrict__ part_in,
    const float* __restrict__ r, float* __restrict__ p, __half* __restrict__ ph) {
  float gamma = scal[2 + k], atol2 = scal[1];
  if (!(gamma > atol2)) {
    if (blockIdx.x == 0 && threadIdx.x == 0) scal[2 + k + 1] = gamma;  // propagate
    return;
  }
  __shared__ float red[256];
  float lp = 0.f;
  for (int i = threadIdx.x; i < XB; i += VT) lp += part_in[i];
  float gnew = block_reduce_256(lp, red);
  float beta = gnew / gamma;
  const float4* r4 = (const float4*)r;
  float4* p4 = (float4*)p;
  int stride = gridDim.x * blockDim.x;
  for (int e = blockIdx.x * blockDim.x + threadIdx.x; e < NC_TOT / 4; e += stride) {
    float4 pe = p4[e], re = r4[e];
    pe.x = fmaf(beta, pe.x, re.x); pe.y = fmaf(beta, pe.y, re.y);
    pe.z = fmaf(beta, pe.z, re.z); pe.w = fmaf(beta, pe.w, re.w);
    p4[e] = pe;
    int e4 = e * 4;
    ph[e4 + 0] = __float2half(pe.x);
    ph[e4 + 1] = __float2half(pe.y);
    ph[e4 + 2] = __float2half(pe.z);
    ph[e4 + 3] = __float2half(pe.w);
  }
  if (blockIdx.x == 0 && threadIdx.x == 0) scal[2 + k + 1] = gnew;
}

// ------------------- host launch -------------------
extern "C" void kernel_launch(void* const* d_in, const int* in_sizes, int n_in,
                              void* d_out, int out_size, void* d_ws, size_t ws_size,
                              hipStream_t stream) {
  const float* feat = (const float*)d_in[0];
  const float* W    = (const float*)d_in[1];
  const float* bias = (const float*)d_in[2];
  const float* e0   = (const float*)d_in[3];
  const float* data = (const float*)d_in[4];
  const int*   row  = (const int*)d_in[5];
  const int*   col  = (const int*)d_in[6];
  const int*   ids  = (const int*)d_in[7];
  float* out = (float*)d_out;

  size_t off = 0;
  char* base = (char*)d_ws;
  auto take = [&](size_t nbytes) -> void* {
    void* ptr = base + off;
    off += (nbytes + 255) & ~(size_t)255;
    return ptr;
  };
  float* rv  = (float*)take((size_t)NC_TOT * 4);
  float* pv  = (float*)take((size_t)NC_TOT * 4);
  float* ap  = (float*)take((size_t)NC_TOT * 4);
  __half* ph = (__half*)take((size_t)NC_TOT * 2);
  int2*  csr = (int2*)take((size_t)NEDGE * 8);
  int* rowptr    = (int*)take((size_t)(NNODE + 1) * 4);
  int* cntmat    = (int*)take((size_t)NPB * NBUCK * 4);   // becomes offmat in-place
  int* total     = (int*)take((size_t)(NBUCK + 2) * 4);
  int* bptr      = (int*)take((size_t)(NBUCK + 2) * 4);
  float* part_a  = (float*)take(SB * 4);
  float* part_b  = (float*)take(XB * 4);
  float* scal    = (float*)take(64 * 4);

  // bucket staging buffer aliases rv+pv (25.6MB <= 32MB); dead before k_gemm
  uint2* bstage = (uint2*)rv;

  // partition-based CSR build
  hipMemsetAsync(total, 0, (size_t)(NBUCK + 2) * 4, stream);
  hipMemsetAsync(out, 0, (size_t)NIDS * NCLS * 4, stream);
  k_pcount<<<NPB, 256, 0, stream>>>(row, cntmat, total);
  k_bscan2<<<1, 1024, 0, stream>>>(total, bptr);
  k_colscan<<<NBUCK, 1024, 0, stream>>>(cntmat, bptr);
  k_ppart<<<NPB, 512, 0, stream>>>(row, col, data, cntmat, bstage);
  k_bbuild<<<NBUCK, 512, 0, stream>>>(bptr, bstage, rowptr, csr);

  // init: b_vec, r0=p0=b_vec (+fp16 mirror), gamma0=<b,b>
  k_gemm<<<GEMM_B, 256, 0, stream>>>(feat, W, bias, rv, pv, ph, part_a);
  k_init_scal<<<1, 256, 0, stream>>>(part_a, e0, scal);

  // 16 unrolled, device-guarded CG iterations
  for (int k = 0; k < MAXIT; ++k) {
    k_spmv<<<SB, VT, 0, stream>>>(scal, k, rowptr, csr, ph, pv, ap, part_a);
    k_xr  <<<XB, VT, 0, stream>>>(scal, k, part_a, pv, ap, rv, ids, out, part_b);
    k_pupd<<<XB, VT, 0, stream>>>(scal, k, part_b, rv, pv, ph);
  }
}